// Round 25
// baseline (65.904 us; speedup 1.0000x reference)
//
#include <hip/hip_runtime.h>

#define IMG 512
#define BATCH 64
#define RPS 64          // output rows per strip
#define NSTEP 74        // RPS + 10 halo rows
#define WPW 144         // words per wave-row buffer (140 used + pad)

typedef float v2f __attribute__((ext_vector_type(2)));

__global__ __launch_bounds__(256, 2) void ssim_fold_kernel(
    const float* __restrict__ img1, const float* __restrict__ img2,
    const float* __restrict__ window, float* __restrict__ partials)
{
    __shared__ float S[4][2][2][WPW];    // [wave][buf][img][word]  9216 B
    __shared__ float wred[4];

    const int tid   = threadIdx.x;
    const int lane  = tid & 63;
    const int wv    = tid >> 6;          // wave 0..3
    const int strip = blockIdx.x;        // 0..7
    const int b     = blockIdx.y;        // batch
    const int r_base = strip * RPS;
    const int cbase = wv * 128;          // wave's first output col
    const int c0    = cbase + lane * 2;  // own cols c0, c0+1

    // 1-D gaussian = row sums of the 11x11 window; force to SGPR
    float gw[11];
    #pragma unroll
    for (int k = 0; k < 11; ++k) {
        float s = 0.f;
        #pragma unroll
        for (int j = 0; j < 11; ++j) s += window[k*11 + j];
        gw[k] = __int_as_float(__builtin_amdgcn_readfirstlane(__float_as_int(s)));
    }

    const float* P1 = img1 + (size_t)b * (IMG*IMG);
    const float* P2 = img2 + (size_t)b * (IMG*IMG);

    // halo duty: 3 left lanes + 3 right lanes per wave
    const bool lh = (lane < 3);
    const bool rh = (lane >= 61);
    const int  lcol = cbase - 6 + 2*lane;
    const int  rcol = cbase + 128 + 2*(lane - 61);
    const bool lok = lh && (lcol >= 0);
    const bool rok = rh && (rcol <= IMG-2);

    // fetch row rr: own pair + (for duty lanes) halo pair. Zeros when OOB.
    auto fetch = [&](int rr, v2f& o1, v2f& o2, v2f& h1_, v2f& h2_) {
        o1=(v2f){0,0}; o2=(v2f){0,0}; h1_=(v2f){0,0}; h2_=(v2f){0,0};
        if (rr >= 0 && rr < IMG) {
            const float* q1 = P1 + (size_t)rr*IMG;
            const float* q2 = P2 + (size_t)rr*IMG;
            o1 = *(const v2f*)(q1 + c0);
            o2 = *(const v2f*)(q2 + c0);
            if (lok) { h1_ = *(const v2f*)(q1 + lcol); h2_ = *(const v2f*)(q2 + lcol); }
            if (rok) { h1_ = *(const v2f*)(q1 + rcol); h2_ = *(const v2f*)(q2 + rcol); }
        }
    };
    // store into this wave's buffer `buf` (same-wave ds ops -> in-order, no barrier)
    auto store = [&](int buf, v2f o1, v2f o2, v2f h1_, v2f h2_) {
        *(v2f*)&S[wv][buf][0][6 + 2*lane] = o1;
        *(v2f*)&S[wv][buf][1][6 + 2*lane] = o2;
        if (lh) { *(v2f*)&S[wv][buf][0][2*lane] = h1_;
                  *(v2f*)&S[wv][buf][1][2*lane] = h2_; }
        if (rh) { *(v2f*)&S[wv][buf][0][134 + 2*(lane-61)] = h1_;
                  *(v2f*)&S[wv][buf][1][134 + 2*(lane-61)] = h2_; }
    };

    // depth-2 pipeline slots (flat named v2f)
    v2f pAo1, pAo2, pAh1, pAh2;          // stored at even u
    v2f pBo1, pBo2, pBh1, pBh2;          // stored at odd u

    // rolling register forward of the lane's OWN column pair
    v2f ownC1, ownC2, ownN1, ownN2;

    // prologue: row r_base-5 -> buf0 directly; A <- row -4 (store at t=0),
    // B <- row -3 (store at t=1).
    { v2f o1,o2,e1,e2; fetch(r_base - 5, o1,o2,e1,e2); store(0, o1,o2,e1,e2);
      ownC1 = o1; ownC2 = o2; }
    fetch(r_base - 4, pAo1,pAo2,pAh1,pAh2);
    fetch(r_base - 3, pBo1,pBo2,pBh1,pBh2);

    // 11-slot ring of vertical accumulators: 4 channels {x, y, x^2+y^2, xy}, packed.
    // Slot s is ASSIGNED (not zero+add) on its first tap (k=0), so no explicit
    // zeroing is needed in the loop; only warm-up validity for t<11 requires the
    // init below (slots whose first-assign happens at t = s are fine; initial
    // zeros are only read if finalized before 11 taps, which t>=10 guard forbids).
    v2f acc[11][4];
    #pragma unroll
    for (int s = 0; s < 11; ++s)
        #pragma unroll
        for (int ch = 0; ch < 4; ++ch) acc[s][ch] = (v2f){0.f, 0.f};

    v2f rsum = (v2f){0.f, 0.f};
    const float C1 = 1e-4f, C2 = 9e-4f;

    #pragma unroll 1
    for (int jj = 0; jj < 7; ++jj) {
      #pragma unroll
      for (int u = 0; u < 11; ++u) {
        if (jj < 6 || u < 8) {               // t < NSTEP (74 = 6*11 + 8)
          const int t = jj*11 + u;
          const int rr = r_base - 5 + t;

          // ---- memory-issue phase (prio 0) ----
          // (1) store row rr+1 (fetched 2 steps ago); save own pair for next step
          if ((u & 1) == 0) {
            store((t+1) & 1, pAo1,pAo2,pAh1,pAh2);
            ownN1 = pAo1; ownN2 = pAo2;
          } else {
            store((t+1) & 1, pBo1,pBo2,pBh1,pBh2);
            ownN1 = pBo1; ownN2 = pBo2;
          }

          // (2) read this step's 14-col window: 6 x b64 per image (own pair forwarded)
          const float* R1 = &S[wv][t & 1][0][0];
          const float* R2 = &S[wv][t & 1][1][0];
          v2f L1[7], L2[7];                  // L[q] = cols c0-6+2q, c0-5+2q
          #pragma unroll
          for (int q = 0; q < 7; ++q) {
            if (q == 3) { L1[3] = ownC1; L2[3] = ownC2; }
            else {
              L1[q] = *(const v2f*)&R1[2*lane + 2*q];
              L2[q] = *(const v2f*)&R2[2*lane + 2*q];
            }
          }

          // (3) refill the just-consumed slot with row rr+3 (2 steps ahead)
          if ((u & 1) == 0) fetch(rr + 3, pAo1,pAo2,pAh1,pAh2);
          else              fetch(rr + 3, pBo1,pBo2,pBh1,pBh2);

          // ---- compute phase (prio 1) ----
          __builtin_amdgcn_s_setprio(1);

          // (4) packed horizontal conv, 4 channels
          v2f h0 = (v2f){0,0}, hy = (v2f){0,0};
          v2f hs = (v2f){0,0}, hx = (v2f){0,0};
          #pragma unroll
          for (int k = 0; k < 11; ++k) {
            v2f pa, pb;
            if (k & 1) {                     // k odd: natural pair L[(k+1)/2]
              pa = L1[(k+1) >> 1]; pb = L2[(k+1) >> 1];
            } else {                         // k even: straddling pair
              pa = __builtin_shufflevector(L1[k>>1], L1[(k>>1)+1], 1, 2);
              pb = __builtin_shufflevector(L2[k>>1], L2[(k>>1)+1], 1, 2);
            }
            float w = gw[k];
            h0 += w * pa;
            hy += w * pb;
            hs += w * (pa*pa + pb*pb);
            hx += w * (pa * pb);
          }

          // (5) ring accumulate: slot s takes tap k = 10 - ((s-u) mod 11).
          //     k==0 (first tap, the slot finalized LAST step) is ASSIGNED:
          //     replaces the old zero+add pair.
          #pragma unroll
          for (int s = 0; s < 11; ++s) {
            const int km = ((s - u) % 11 + 11) % 11;
            const int k  = 10 - km;
            const float w = gw[k];
            if (k == 0) {
              acc[s][0] = w * h0;
              acc[s][1] = w * hy;
              acc[s][2] = w * hs;
              acc[s][3] = w * hx;
            } else {
              acc[s][0] += w * h0;
              acc[s][1] += w * hy;
              acc[s][2] += w * hs;
              acc[s][3] += w * hx;
            }
          }

          // (6) slot u completed its 11 taps (out-row r_base - 10 + t).
          //     NOTE: slot u's k==10 tap was applied in (5) (km==0 for s==u).
          if (t >= 10) {
            v2f mu1 = acc[u][0], mu2 = acc[u][1];
            v2f mu1s = mu1*mu1, mu2s = mu2*mu2, mu12 = mu1*mu2;
            v2f sigs  = acc[u][2] - mu1s - mu2s;   // sigma1^2 + sigma2^2
            v2f sig12 = acc[u][3] - mu12;
            v2f num = (2.f*mu12 + C1) * (2.f*sig12 + C2);
            v2f den = (mu1s + mu2s + C1) * (sigs + C2);
            rsum.x += num.x * __builtin_amdgcn_rcpf(den.x);
            rsum.y += num.y * __builtin_amdgcn_rcpf(den.y);
          }
          // (no zeroing: slot u is re-assigned on its next k==0 tap, next step)

          __builtin_amdgcn_s_setprio(0);

          // (7) roll the own-pair forward
          ownC1 = ownN1; ownC2 = ownN2;
        }
      }
      // 11 is odd: swap pend roles so next jj keeps compile-time parity
      { v2f x;
        x=pAo1; pAo1=pBo1; pBo1=x;  x=pAo2; pAo2=pBo2; pBo2=x;
        x=pAh1; pAh1=pBh1; pBh1=x;  x=pAh2; pAh2=pBh2; pBh2=x; }
    }

    float thr_sum = rsum.x + rsum.y;

    // block reduction (single barrier, after the loop)
    for (int d = 32; d > 0; d >>= 1) thr_sum += __shfl_down(thr_sum, d, 64);
    if (lane == 0) wred[wv] = thr_sum;
    __syncthreads();
    if (tid == 0) {
        float s = wred[0] + wred[1] + wred[2] + wred[3];
        partials[blockIdx.y * 8 + blockIdx.x] = s;
    }
}

__global__ __launch_bounds__(256) void ssim_reduce_kernel(
    const float* __restrict__ partials, int n, float* __restrict__ out)
{
    __shared__ double wsumd[4];
    double s = 0.0;
    for (int i = threadIdx.x; i < n; i += 256) s += (double)partials[i];
    for (int d = 32; d > 0; d >>= 1) s += __shfl_down(s, d, 64);
    int wid = threadIdx.x >> 6, lane = threadIdx.x & 63;
    if (lane == 0) wsumd[wid] = s;
    __syncthreads();
    if (threadIdx.x == 0) {
        double t = wsumd[0] + wsumd[1] + wsumd[2] + wsumd[3];
        out[0] = (float)(t / ((double)BATCH * IMG * IMG));
    }
}

extern "C" void kernel_launch(void* const* d_in, const int* in_sizes, int n_in,
                              void* d_out, int out_size, void* d_ws, size_t ws_size,
                              hipStream_t stream) {
    const float* img1   = (const float*)d_in[0];
    const float* img2   = (const float*)d_in[1];
    const float* window = (const float*)d_in[2];
    float* out = (float*)d_out;
    float* partials = (float*)d_ws;

    dim3 grid(IMG / RPS, BATCH);   // 8 x 64 = 512 blocks (2 per CU exactly)
    ssim_fold_kernel<<<grid, dim3(256), 0, stream>>>(img1, img2, window, partials);

    int npart = (IMG / RPS) * BATCH;  // 512
    ssim_reduce_kernel<<<1, 256, 0, stream>>>(partials, npart, out);
}

// Round 26
// 63.054 us; speedup vs baseline: 1.0452x; 1.0452x over previous
//
#include <hip/hip_runtime.h>

#define IMG 512
#define BATCH 64
#define RPS 64          // output rows per strip
#define NSTEP 74        // RPS + 10 halo rows
#define WPW 144         // words per wave-row buffer (140 used + pad)

typedef float v2f __attribute__((ext_vector_type(2)));

__global__ __launch_bounds__(256, 2) void ssim_zd_kernel(
    const float* __restrict__ img1, const float* __restrict__ img2,
    const float* __restrict__ window, float* __restrict__ partials)
{
    __shared__ float S[4][2][2][WPW];    // [wave][buf][ch: 0=z,1=d][word]  9216 B
    __shared__ float wred[4];

    const int tid   = threadIdx.x;
    const int lane  = tid & 63;
    const int wv    = tid >> 6;          // wave 0..3
    const int strip = blockIdx.x;        // 0..7
    const int b     = blockIdx.y;        // batch
    const int r_base = strip * RPS;
    const int cbase = wv * 128;          // wave's first output col
    const int c0    = cbase + lane * 2;  // own cols c0, c0+1

    // 1-D gaussian = row sums of the 11x11 window; force to SGPR
    float gw[11];
    #pragma unroll
    for (int k = 0; k < 11; ++k) {
        float s = 0.f;
        #pragma unroll
        for (int j = 0; j < 11; ++j) s += window[k*11 + j];
        gw[k] = __int_as_float(__builtin_amdgcn_readfirstlane(__float_as_int(s)));
    }

    const float* P1 = img1 + (size_t)b * (IMG*IMG);
    const float* P2 = img2 + (size_t)b * (IMG*IMG);

    // halo duty: 3 left lanes + 3 right lanes per wave
    const bool lh = (lane < 3);
    const bool rh = (lane >= 61);
    const int  lcol = cbase - 6 + 2*lane;
    const int  rcol = cbase + 128 + 2*(lane - 61);
    const bool lok = lh && (lcol >= 0);
    const bool rok = rh && (rcol <= IMG-2);

    // fetch row rr: RAW x,y pairs (transform deferred to store so the vmcnt
    // wait stays 2 steps downstream). Zeros when OOB.
    auto fetch = [&](int rr, v2f& o1, v2f& o2, v2f& h1_, v2f& h2_) {
        o1=(v2f){0,0}; o2=(v2f){0,0}; h1_=(v2f){0,0}; h2_=(v2f){0,0};
        if (rr >= 0 && rr < IMG) {
            const float* q1 = P1 + (size_t)rr*IMG;
            const float* q2 = P2 + (size_t)rr*IMG;
            o1 = *(const v2f*)(q1 + c0);
            o2 = *(const v2f*)(q2 + c0);
            if (lok) { h1_ = *(const v2f*)(q1 + lcol); h2_ = *(const v2f*)(q2 + lcol); }
            if (rok) { h1_ = *(const v2f*)(q1 + rcol); h2_ = *(const v2f*)(q2 + rcol); }
        }
    };
    // store z=x+y, d=x-y into this wave's buffer (same-wave ds ops -> no barrier)
    auto store = [&](int buf, v2f o1, v2f o2, v2f h1_, v2f h2_) {
        *(v2f*)&S[wv][buf][0][6 + 2*lane] = o1 + o2;
        *(v2f*)&S[wv][buf][1][6 + 2*lane] = o1 - o2;
        if (lh) { *(v2f*)&S[wv][buf][0][2*lane] = h1_ + h2_;
                  *(v2f*)&S[wv][buf][1][2*lane] = h1_ - h2_; }
        if (rh) { *(v2f*)&S[wv][buf][0][134 + 2*(lane-61)] = h1_ + h2_;
                  *(v2f*)&S[wv][buf][1][134 + 2*(lane-61)] = h1_ - h2_; }
    };

    // depth-2 pipeline slots (flat named v2f, raw x/y)
    v2f pAo1, pAo2, pAh1, pAh2;          // stored at even u
    v2f pBo1, pBo2, pBh1, pBh2;          // stored at odd u

    // rolling register forward of the lane's OWN z,d pair
    v2f ownC1, ownC2, ownN1, ownN2;

    // prologue: row r_base-5 -> buf0 directly; A <- row -4 (store at t=0),
    // B <- row -3 (store at t=1).
    { v2f o1,o2,e1,e2; fetch(r_base - 5, o1,o2,e1,e2); store(0, o1,o2,e1,e2);
      ownC1 = o1 + o2; ownC2 = o1 - o2; }
    fetch(r_base - 4, pAo1,pAo2,pAh1,pAh2);
    fetch(r_base - 3, pBo1,pBo2,pBh1,pBh2);

    // 11-slot ring of vertical accumulators: 4 channels {z, d, z^2, d^2}, packed
    v2f acc[11][4];
    #pragma unroll
    for (int s = 0; s < 11; ++s)
        #pragma unroll
        for (int ch = 0; ch < 4; ++ch) acc[s][ch] = (v2f){0.f, 0.f};

    v2f rsum = (v2f){0.f, 0.f};
    const float C1 = 1e-4f, C2 = 9e-4f;

    #pragma unroll 1
    for (int jj = 0; jj < 7; ++jj) {
      #pragma unroll
      for (int u = 0; u < 11; ++u) {
        if (jj < 6 || u < 8) {               // t < NSTEP (74 = 6*11 + 8)
          const int t = jj*11 + u;
          const int rr = r_base - 5 + t;

          // ---- memory-issue phase (prio 0) ----
          // (1) store row rr+1 (fetched 2 steps ago); save its z,d own pair
          if ((u & 1) == 0) {
            store((t+1) & 1, pAo1,pAo2,pAh1,pAh2);
            ownN1 = pAo1 + pAo2; ownN2 = pAo1 - pAo2;
          } else {
            store((t+1) & 1, pBo1,pBo2,pBh1,pBh2);
            ownN1 = pBo1 + pBo2; ownN2 = pBo1 - pBo2;
          }

          // (2) read this step's 14-col window: 6 x b64 per channel (own forwarded)
          const float* R1 = &S[wv][t & 1][0][0];   // z
          const float* R2 = &S[wv][t & 1][1][0];   // d
          v2f L1[7], L2[7];                  // L[q] = cols c0-6+2q, c0-5+2q
          #pragma unroll
          for (int q = 0; q < 7; ++q) {
            if (q == 3) { L1[3] = ownC1; L2[3] = ownC2; }
            else {
              L1[q] = *(const v2f*)&R1[2*lane + 2*q];
              L2[q] = *(const v2f*)&R2[2*lane + 2*q];
            }
          }

          // (3) refill the just-consumed slot with row rr+3 (2 steps ahead)
          if ((u & 1) == 0) fetch(rr + 3, pAo1,pAo2,pAh1,pAh2);
          else              fetch(rr + 3, pBo1,pBo2,pBh1,pBh2);

          // ---- compute phase (prio 1) ----
          __builtin_amdgcn_s_setprio(1);

          // (4) packed horizontal conv, 4 channels {z, d, z^2, d^2}
          v2f hz = (v2f){0,0}, hd = (v2f){0,0};
          v2f hz2 = (v2f){0,0}, hd2 = (v2f){0,0};
          #pragma unroll
          for (int k = 0; k < 11; ++k) {
            v2f pa, pb;
            if (k & 1) {                     // k odd: natural pair L[(k+1)/2]
              pa = L1[(k+1) >> 1]; pb = L2[(k+1) >> 1];
            } else {                         // k even: straddling pair
              pa = __builtin_shufflevector(L1[k>>1], L1[(k>>1)+1], 1, 2);
              pb = __builtin_shufflevector(L2[k>>1], L2[(k>>1)+1], 1, 2);
            }
            float w = gw[k];
            hz  += w * pa;
            hd  += w * pb;
            hz2 += w * (pa * pa);
            hd2 += w * (pb * pb);
          }

          // (5) packed vertical ring accumulate: slot s takes tap k = 10 - ((s-u) mod 11)
          #pragma unroll
          for (int s = 0; s < 11; ++s) {
            const int k = 10 - (((s - u) % 11 + 11) % 11);
            const float w = gw[k];
            acc[s][0] += w * hz;
            acc[s][1] += w * hd;
            acc[s][2] += w * hz2;
            acc[s][3] += w * hd2;
          }

          // (6) slot u completed its 11 taps (out-row r_base - 10 + t)
          // Identities: A=vz^2+vd^2=2(mu1^2+mu2^2), B=vz^2-vd^2=4*mu1*mu2,
          //             S=VZ2+VD2=2*conv(x^2+y^2),  D=VZ2-VD2=4*conv(xy)
          if (t >= 10) {
            v2f vz = acc[u][0], vd = acc[u][1];
            v2f VZ2 = acc[u][2], VD2 = acc[u][3];
            v2f z2 = vz*vz, d2 = vd*vd;
            v2f A = z2 + d2, B = z2 - d2;
            v2f Ssum = VZ2 + VD2, D = VZ2 - VD2;
            v2f num = (0.5f*B + C1) * (0.5f*(D - B) + C2);
            v2f den = (0.5f*A + C1) * (0.5f*(Ssum - A) + C2);
            rsum.x += num.x * __builtin_amdgcn_rcpf(den.x);
            rsum.y += num.y * __builtin_amdgcn_rcpf(den.y);
          }
          #pragma unroll
          for (int ch = 0; ch < 4; ++ch) acc[u][ch] = (v2f){0.f, 0.f};

          __builtin_amdgcn_s_setprio(0);

          // (7) roll the own z,d pair forward
          ownC1 = ownN1; ownC2 = ownN2;
        }
      }
      // 11 is odd: swap pend roles so next jj keeps compile-time parity
      { v2f x;
        x=pAo1; pAo1=pBo1; pBo1=x;  x=pAo2; pAo2=pBo2; pBo2=x;
        x=pAh1; pAh1=pBh1; pBh1=x;  x=pAh2; pAh2=pBh2; pBh2=x; }
    }

    float thr_sum = rsum.x + rsum.y;

    // block reduction (single barrier, after the loop)
    for (int d = 32; d > 0; d >>= 1) thr_sum += __shfl_down(thr_sum, d, 64);
    if (lane == 0) wred[wv] = thr_sum;
    __syncthreads();
    if (tid == 0) {
        float s = wred[0] + wred[1] + wred[2] + wred[3];
        partials[blockIdx.y * 8 + blockIdx.x] = s;
    }
}

__global__ __launch_bounds__(256) void ssim_reduce_kernel(
    const float* __restrict__ partials, int n, float* __restrict__ out)
{
    __shared__ double wsumd[4];
    double s = 0.0;
    for (int i = threadIdx.x; i < n; i += 256) s += (double)partials[i];
    for (int d = 32; d > 0; d >>= 1) s += __shfl_down(s, d, 64);
    int wid = threadIdx.x >> 6, lane = threadIdx.x & 63;
    if (lane == 0) wsumd[wid] = s;
    __syncthreads();
    if (threadIdx.x == 0) {
        double t = wsumd[0] + wsumd[1] + wsumd[2] + wsumd[3];
        out[0] = (float)(t / ((double)BATCH * IMG * IMG));
    }
}

extern "C" void kernel_launch(void* const* d_in, const int* in_sizes, int n_in,
                              void* d_out, int out_size, void* d_ws, size_t ws_size,
                              hipStream_t stream) {
    const float* img1   = (const float*)d_in[0];
    const float* img2   = (const float*)d_in[1];
    const float* window = (const float*)d_in[2];
    float* out = (float*)d_out;
    float* partials = (float*)d_ws;

    dim3 grid(IMG / RPS, BATCH);   // 8 x 64 = 512 blocks (2 per CU exactly)
    ssim_zd_kernel<<<grid, dim3(256), 0, stream>>>(img1, img2, window, partials);

    int npart = (IMG / RPS) * BATCH;  // 512
    ssim_reduce_kernel<<<1, 256, 0, stream>>>(partials, npart, out);
}